// Round 9
// baseline (90.464 us; speedup 1.0000x reference)
//
#include <hip/hip_runtime.h>

#define N_ 8
#define C_ 64
#define P_ 4096

typedef float f32x4 __attribute__((ext_vector_type(4)));
typedef short bf16x8 __attribute__((ext_vector_type(8)));

__device__ __forceinline__ unsigned short f2bf(float f) {
  unsigned int u = __builtin_bit_cast(unsigned int, f);
  u = (u + 0x7fffu + ((u >> 16) & 1u)) >> 16;  // RNE
  return (unsigned short)u;
}

// Kernel 1: L2-normalize along C, write bf16 transposed to [N][P][C].
// rgb side pre-scaled by 10*log2(e) so the GEMM epilogue is exp2(acc).
// ir side written with a 16B-group XOR swizzle (g ^= p&7) per row so a LINEAR
// global_load_lds copy yields a bank-conflict-free LDS layout (T2, rule #21).
__global__ void __launch_bounds__(256) norm_transpose(
    const float* __restrict__ rgb, const float* __restrict__ ir,
    unsigned short* __restrict__ rgbnT, unsigned short* __restrict__ irnT) {
  const int idx = blockIdx.x * 256 + threadIdx.x;  // over N*P
  const int n = idx >> 12;
  const int p = idx & (P_ - 1);
  const float* src = (blockIdx.y == 0) ? rgb : ir;
  unsigned short* dst = (blockIdx.y == 0) ? rgbnT : irnT;
  const float SC = 14.4269504088896340736f;  // 10*log2(e)
  const float* col = src + (size_t)n * C_ * P_ + p;
  float v[C_];
  float ss = 0.f;
#pragma unroll
  for (int c = 0; c < C_; ++c) {
    v[c] = col[(size_t)c * P_];
    ss += v[c] * v[c];
  }
  float inv = 1.0f / fmaxf(sqrtf(ss), 1e-12f);
  if (blockIdx.y == 0) inv *= SC;
  const int gx = (blockIdx.y == 0) ? 0 : (p & 7);  // swizzle only ir
  unsigned short* o = dst + ((size_t)n * P_ + p) * C_;
#pragma unroll
  for (int g = 0; g < 8; ++g) {
    bf16x8 pack;
#pragma unroll
    for (int j = 0; j < 8; ++j) pack[j] = (short)f2bf(v[g * 8 + j] * inv);
    *reinterpret_cast<bf16x8*>(o + (g ^ gx) * 8) = pack;
  }
}

// Async global->LDS: 8KB tile (64 q-rows x 64 c), 256 threads x 2 x 16B.
// LDS dest is wave-uniform base + lane*16 (hardware rule); source is per-lane.
__device__ __forceinline__ void stage_tile(const unsigned short* src,
                                           unsigned short* dst, int tid,
                                           int wid) {
#pragma unroll
  for (int r = 0; r < 2; ++r) {
    __builtin_amdgcn_global_load_lds(
        (const __attribute__((address_space(1))) void*)(src +
                                                        (size_t)(r * 256 + tid) * 8),
        (__attribute__((address_space(3))) void*)(dst + (r * 256 + wid * 64) * 8),
        16, 0, 0);
  }
}

// Kernel 2: block = 128p x 512q (8 q-tiles of 64). 4 waves stacked on p,
// 32 rows each -> acc[2][4]=32 + af=16 + bf_=32 ~= 110 live regs, inside the
// <=128 VGPR / 4-waves-per-SIMD occupancy window (R3@108: 27% occ vs
// R8@152: 9% occ). B tiles double-buffered in LDS via global_load_lds.
// Grid 2048 blocks / 8192 waves; n = blockIdx.x & 7 (XCD L2 locality).
// Spill discipline (R4/R6/R7): bare launch_bounds(256), 256-thread blocks,
// t-loop `#pragma unroll 2` ONLY (R7's full unroll spilled at this geometry).
__global__ void __launch_bounds__(256) gemm_exp_reduce(
    const unsigned short* __restrict__ aT, const unsigned short* __restrict__ bT,
    float* __restrict__ partials) {
  const int lin = blockIdx.x;
  const int n = lin & 7;
  const int local = lin >> 3;
  const int pc = local & 31;  // 32 p-chunks of 128
  const int qc = local >> 5;  // 8 q-chunks of 512
  const int tid = threadIdx.x;
  const int lane = tid & 63;
  const int wid = tid >> 6;  // 4 waves
  const int pbase = pc * 128 + wid * 32;
  const int q0 = qc * 512;
  const unsigned short* A = aT + (size_t)n * P_ * C_;  // [P][C] linear
  const unsigned short* B = bT + (size_t)n * P_ * C_;  // [P][C] swizzled rows
  const int r16 = lane & 15;
  const int kofs = (lane >> 4) * 8;

  __shared__ __align__(16) unsigned short bs[2][64 * 64];

  // A fragments: register-resident for the whole kernel (16 VGPR).
  bf16x8 af[2][2];
#pragma unroll
  for (int ks = 0; ks < 2; ++ks)
#pragma unroll
    for (int mi = 0; mi < 2; ++mi)
      af[ks][mi] = *reinterpret_cast<const bf16x8*>(
          A + (size_t)(pbase + mi * 16 + r16) * C_ + ks * 32 + kofs);

  stage_tile(B + (size_t)q0 * C_, bs[0], tid, wid);
  __syncthreads();  // drains vmcnt -> bs[0] ready

  float t0 = 0.f, t1 = 0.f, t2 = 0.f, t3 = 0.f, pos = 0.f;
  const int col = lane & 15;
  const int rowb = (lane >> 4) * 4;

#pragma unroll 2
  for (int t = 0; t < 8; ++t) {
    const int cur = t & 1;
    if (t < 7)  // prefetch next tile into the other buffer (async, 0 VGPR)
      stage_tile(B + (size_t)(q0 + (t + 1) * 64) * C_, bs[cur ^ 1], tid, wid);

    // LDS -> B fragments (swizzled read matches pre-swizzled global rows)
    const unsigned short* bp = bs[cur];
    bf16x8 bf_[2][4];
#pragma unroll
    for (int ks = 0; ks < 2; ++ks)
#pragma unroll
      for (int ni = 0; ni < 4; ++ni) {
        const int row = ni * 16 + r16;
        const int seg = ks * 4 + (lane >> 4);
        bf_[ks][ni] = *reinterpret_cast<const bf16x8*>(
            bp + row * 64 + ((seg ^ (lane & 7)) * 8));
      }

    f32x4 acc[2][4];
#pragma unroll
    for (int i = 0; i < 2; ++i)
#pragma unroll
      for (int j = 0; j < 4; ++j) acc[i][j] = (f32x4)(0.f);

#pragma unroll
    for (int ks = 0; ks < 2; ++ks)
#pragma unroll
      for (int mi = 0; mi < 2; ++mi)
#pragma unroll
        for (int ni = 0; ni < 4; ++ni)
          acc[mi][ni] = __builtin_amdgcn_mfma_f32_16x16x32_bf16(
              af[ks][mi], bf_[ks][ni], acc[mi][ni], 0, 0, 0);

    // Epilogue: logit = exp2(acc); 4 independent accumulators.
#pragma unroll
    for (int mi = 0; mi < 2; ++mi)
#pragma unroll
      for (int ni = 0; ni < 4; ++ni) {
        const f32x4 v = acc[mi][ni];
        t0 += __builtin_amdgcn_exp2f(v[0]);
        t1 += __builtin_amdgcn_exp2f(v[1]);
        t2 += __builtin_amdgcn_exp2f(v[2]);
        t3 += __builtin_amdgcn_exp2f(v[3]);
      }
    const int qb = q0 + t * 64;
    const int dq = pbase - qb;  // wave's 32 rows overlap this 64-col tile?
    if ((unsigned)dq < 64u) {   // dq in {0, 32}
#pragma unroll
      for (int mi = 0; mi < 2; ++mi) {
        const int ni = (dq >> 4) + mi;  // frag with gq0 == gp0
#pragma unroll
        for (int r = 0; r < 4; ++r)
          if (rowb + r == col) pos += __builtin_amdgcn_exp2f(acc[mi][ni][r]);
      }
    }

    __syncthreads();  // stage(t+1) complete + all waves done with bs[cur]
  }

  float tot = (t0 + t1) + (t2 + t3);
#pragma unroll
  for (int off = 32; off > 0; off >>= 1) {
    tot += __shfl_down(tot, off);
    pos += __shfl_down(pos, off);
  }
  __shared__ float sb[8];
  if (lane == 0) { sb[wid * 2] = pos; sb[wid * 2 + 1] = tot; }
  __syncthreads();
  if (tid == 0) {
    const float pp = sb[0] + sb[2] + sb[4] + sb[6];
    const float tt = sb[1] + sb[3] + sb[5] + sb[7];
    const int bid = n * 256 + pc * 8 + qc;
    partials[bid * 2] = pp;
    partials[bid * 2 + 1] = tt;
  }
}

// Kernel 3: reduce 256 partial pairs per n, compute loss. One pass.
__global__ void __launch_bounds__(1024) finalize(
    const float* __restrict__ partials, float* __restrict__ out) {
  const int tid = threadIdx.x;
  const int lane = tid & 63, wid = tid >> 6;  // 16 waves; 2 waves per n
  __shared__ float sp[16], st[16], sl[8];
  const int n = tid >> 7;
  const int i = tid & 127;
  float p = partials[(n * 256 + i) * 2] + partials[(n * 256 + i + 128) * 2];
  float t = partials[(n * 256 + i) * 2 + 1] + partials[(n * 256 + i + 128) * 2 + 1];
#pragma unroll
  for (int off = 32; off > 0; off >>= 1) {
    p += __shfl_down(p, off);
    t += __shfl_down(t, off);
  }
  if (lane == 0) { sp[wid] = p; st[wid] = t; }
  __syncthreads();
  if (tid < 8) {
    const float pp = sp[2 * tid] + sp[2 * tid + 1];
    const float tt = st[2 * tid] + st[2 * tid + 1];
    sl[tid] = -logf(pp / (tt + 1e-6f));
  }
  __syncthreads();
  if (tid == 0) {
    float loss = 0.f;
#pragma unroll
    for (int k = 0; k < 8; ++k) loss += sl[k];
    out[0] = loss * (1.0f / N_);
  }
}

extern "C" void kernel_launch(void* const* d_in, const int* in_sizes, int n_in,
                              void* d_out, int out_size, void* d_ws, size_t ws_size,
                              hipStream_t stream) {
  const float* rgb = (const float*)d_in[0];
  const float* ir = (const float*)d_in[1];
  float* out = (float*)d_out;

  unsigned short* rgbnT = (unsigned short*)d_ws;              // 4 MB
  unsigned short* irnT = rgbnT + (size_t)N_ * P_ * C_;        // 4 MB
  float* partials = (float*)(irnT + (size_t)N_ * P_ * C_);    // 16 KB

  dim3 g1(N_ * P_ / 256, 2);
  norm_transpose<<<g1, 256, 0, stream>>>(rgb, ir, rgbnT, irnT);

  gemm_exp_reduce<<<2048, 256, 0, stream>>>(rgbnT, irnT, partials);

  finalize<<<1, 1024, 0, stream>>>(partials, out);
}

// Round 10
// 40.332 us; speedup vs baseline: 2.2430x; 2.2430x over previous
//
#include <hip/hip_runtime.h>

#define N_ 8
#define C_ 64
#define P_ 4096

typedef float f32x4 __attribute__((ext_vector_type(4)));
typedef short bf16x8 __attribute__((ext_vector_type(8)));

__device__ __forceinline__ unsigned short f2bf(float f) {
  unsigned int u = __builtin_bit_cast(unsigned int, f);
  u = (u + 0x7fffu + ((u >> 16) & 1u)) >> 16;  // RNE
  return (unsigned short)u;
}

// Kernel 1: L2-normalize along C, write bf16 transposed to [N][P][C].
// rgb side pre-scaled by 10*log2(e) so the GEMM epilogue is exp2(acc).
// ir side written with a 16B-group XOR swizzle (g ^= p&7) per row so a LINEAR
// global_load_lds copy yields a bank-conflict-free LDS layout (T2, rule #21).
__global__ void __launch_bounds__(256) norm_transpose(
    const float* __restrict__ rgb, const float* __restrict__ ir,
    unsigned short* __restrict__ rgbnT, unsigned short* __restrict__ irnT) {
  const int idx = blockIdx.x * 256 + threadIdx.x;  // over N*P
  const int n = idx >> 12;
  const int p = idx & (P_ - 1);
  const float* src = (blockIdx.y == 0) ? rgb : ir;
  unsigned short* dst = (blockIdx.y == 0) ? rgbnT : irnT;
  const float SC = 14.4269504088896340736f;  // 10*log2(e)
  const float* col = src + (size_t)n * C_ * P_ + p;
  float v[C_];
  float ss = 0.f;
#pragma unroll
  for (int c = 0; c < C_; ++c) {
    v[c] = col[(size_t)c * P_];
    ss += v[c] * v[c];
  }
  float inv = 1.0f / fmaxf(sqrtf(ss), 1e-12f);
  if (blockIdx.y == 0) inv *= SC;
  const int gx = (blockIdx.y == 0) ? 0 : (p & 7);  // swizzle only ir
  unsigned short* o = dst + ((size_t)n * P_ + p) * C_;
#pragma unroll
  for (int g = 0; g < 8; ++g) {
    bf16x8 pack;
#pragma unroll
    for (int j = 0; j < 8; ++j) pack[j] = (short)f2bf(v[g * 8 + j] * inv);
    *reinterpret_cast<bf16x8*>(o + (g ^ gx) * 8) = pack;
  }
}

// Async global->LDS: 8KB tile (64 q-rows x 64 c), 256 threads x 2 x 16B.
// LDS dest is wave-uniform base + lane*16 (hardware rule); source is per-lane.
__device__ __forceinline__ void stage_tile(const unsigned short* src,
                                           unsigned short* dst, int tid,
                                           int wid) {
#pragma unroll
  for (int r = 0; r < 2; ++r) {
    __builtin_amdgcn_global_load_lds(
        (const __attribute__((address_space(1))) void*)(src +
                                                        (size_t)(r * 256 + tid) * 8),
        (__attribute__((address_space(3))) void*)(dst + (r * 256 + wid * 64) * 8),
        16, 0, 0);
  }
}

// Kernel 2: block = 256p x 512q (8 q-tiles of 64). 4 waves x 64 p-rows
// (R5's proven-clean 152-VGPR inner geometry). B tiles in a 3-deep LDS ring
// staged by global_load_lds with COUNTED vmcnt(4) + RAW s_barrier (T3/T4):
// each stage = 2 loads/thread; 3 stages in flight; the barrier never drains
// the queue (__syncthreads would emit vmcnt(0) and expose full load latency
// every iter -- the ~3000 cyc/iter stall that capped R5/R8 at ~40 us).
// Tail: stages wrap modulo 8 into dead buffers so vmcnt(4) stays uniform.
// Spill discipline (R4/R6/R7/R9): bare launch_bounds(256), 256-thr blocks,
// `#pragma unroll 1` main loop, LDS ring via rotated pointers (static idx).
__global__ void __launch_bounds__(256) gemm_exp_reduce(
    const unsigned short* __restrict__ aT, const unsigned short* __restrict__ bT,
    float* __restrict__ partials) {
  const int lin = blockIdx.x;
  const int n = lin & 7;
  const int local = lin >> 3;
  const int pc = local & 15;  // 16 p-chunks of 256
  const int qc = local >> 4;  // 8 q-chunks of 512
  const int tid = threadIdx.x;
  const int lane = tid & 63;
  const int wid = tid >> 6;  // 4 waves
  const int pbase = pc * 256 + wid * 64;
  const int q0 = qc * 512;
  const unsigned short* A = aT + (size_t)n * P_ * C_;  // [P][C] linear
  const unsigned short* B = bT + (size_t)n * P_ * C_;  // [P][C] swizzled rows
  const int r16 = lane & 15;
  const int kofs = (lane >> 4) * 8;

  __shared__ __align__(16) unsigned short bs0[64 * 64];
  __shared__ __align__(16) unsigned short bs1[64 * 64];
  __shared__ __align__(16) unsigned short bs2[64 * 64];

  // A fragments: resident in registers for the whole kernel (32 VGPR).
  bf16x8 af[2][4];
#pragma unroll
  for (int ks = 0; ks < 2; ++ks)
#pragma unroll
    for (int mi = 0; mi < 4; ++mi)
      af[ks][mi] = *reinterpret_cast<const bf16x8*>(
          A + (size_t)(pbase + mi * 16 + r16) * C_ + ks * 32 + kofs);

  // Prologue: fill the ring (6 outstanding loads/thread).
  stage_tile(B + (size_t)(q0 + 0 * 64) * C_, bs0, tid, wid);
  stage_tile(B + (size_t)(q0 + 1 * 64) * C_, bs1, tid, wid);
  stage_tile(B + (size_t)(q0 + 2 * 64) * C_, bs2, tid, wid);

  unsigned short *pcur = bs0, *pnx1 = bs1, *pnx2 = bs2;

  float t0 = 0.f, t1 = 0.f, t2 = 0.f, t3 = 0.f, pos = 0.f;
  const int col = lane & 15;
  const int rowb = (lane >> 4) * 4;

#pragma unroll 1
  for (int t = 0; t < 8; ++t) {
    // Wait for the OLDEST stage only (tile t): 4 newer loads stay in flight.
    asm volatile("s_waitcnt vmcnt(4)" ::: "memory");
    __builtin_amdgcn_sched_barrier(0);
    __builtin_amdgcn_s_barrier();  // all waves' tile-t stage landed (raw!)

    // LDS -> B fragments (swizzled read matches pre-swizzled global rows)
    const unsigned short* bp = pcur;
    bf16x8 bf_[2][4];
#pragma unroll
    for (int ks = 0; ks < 2; ++ks)
#pragma unroll
      for (int ni = 0; ni < 4; ++ni) {
        const int row = ni * 16 + r16;
        const int seg = ks * 4 + (lane >> 4);
        bf_[ks][ni] = *reinterpret_cast<const bf16x8*>(
            bp + row * 64 + ((seg ^ (lane & 7)) * 8));
      }

    f32x4 acc[4][4];
#pragma unroll
    for (int i = 0; i < 4; ++i)
#pragma unroll
      for (int j = 0; j < 4; ++j) acc[i][j] = (f32x4)(0.f);

#pragma unroll
    for (int ks = 0; ks < 2; ++ks)
#pragma unroll
      for (int mi = 0; mi < 4; ++mi)
#pragma unroll
        for (int ni = 0; ni < 4; ++ni)
          acc[mi][ni] = __builtin_amdgcn_mfma_f32_16x16x32_bf16(
              af[ks][mi], bf_[ks][ni], acc[mi][ni], 0, 0, 0);

    // Epilogue: logit = exp2(acc); 4 independent accumulators.
#pragma unroll
    for (int mi = 0; mi < 4; ++mi)
#pragma unroll
      for (int ni = 0; ni < 4; ++ni) {
        const f32x4 v = acc[mi][ni];
        t0 += __builtin_amdgcn_exp2f(v[0]);
        t1 += __builtin_amdgcn_exp2f(v[1]);
        t2 += __builtin_amdgcn_exp2f(v[2]);
        t3 += __builtin_amdgcn_exp2f(v[3]);
      }
    const int qb = q0 + t * 64;
    if (pbase == qb) {  // diagonal subtile
#pragma unroll
      for (int mi = 0; mi < 4; ++mi)
#pragma unroll
        for (int r = 0; r < 4; ++r)
          if (rowb + r == col) pos += __builtin_amdgcn_exp2f(acc[mi][mi][r]);
    }

    __builtin_amdgcn_s_barrier();  // all waves done reading pcur (raw!)

    // Stage tile (t+3) mod 8 into the buffer just freed. Wrapped (dummy)
    // stages keep vmcnt(4) uniform; they write only dead buffers.
    int s = t + 3;
    if (s >= 8) s -= 8;
    stage_tile(B + (size_t)(q0 + s * 64) * C_, pcur, tid, wid);

    // Rotate ring.
    unsigned short* tmp = pcur;
    pcur = pnx1;
    pnx1 = pnx2;
    pnx2 = tmp;
  }

  float tot = (t0 + t1) + (t2 + t3);
#pragma unroll
  for (int off = 32; off > 0; off >>= 1) {
    tot += __shfl_down(tot, off);
    pos += __shfl_down(pos, off);
  }
  __shared__ float sb[8];
  if (lane == 0) { sb[wid * 2] = pos; sb[wid * 2 + 1] = tot; }
  __syncthreads();  // one vmcnt(0) drain here is fine (once per block)
  if (tid == 0) {
    const float pp = sb[0] + sb[2] + sb[4] + sb[6];
    const float tt = sb[1] + sb[3] + sb[5] + sb[7];
    const int bid = n * 128 + pc * 8 + qc;
    partials[bid * 2] = pp;
    partials[bid * 2 + 1] = tt;
  }
}

// Kernel 3: reduce 128 partial pairs per n, compute loss. One pass.
__global__ void __launch_bounds__(1024) finalize(
    const float* __restrict__ partials, float* __restrict__ out) {
  const int tid = threadIdx.x;
  const int lane = tid & 63, wid = tid >> 6;  // 16 waves; 2 waves per n
  __shared__ float sp[16], st[16], sl[8];
  const int n = tid >> 7;
  const int i = tid & 127;
  float p = partials[(n * 128 + i) * 2];
  float t = partials[(n * 128 + i) * 2 + 1];
#pragma unroll
  for (int off = 32; off > 0; off >>= 1) {
    p += __shfl_down(p, off);
    t += __shfl_down(t, off);
  }
  if (lane == 0) { sp[wid] = p; st[wid] = t; }
  __syncthreads();
  if (tid < 8) {
    const float pp = sp[2 * tid] + sp[2 * tid + 1];
    const float tt = st[2 * tid] + st[2 * tid + 1];
    sl[tid] = -logf(pp / (tt + 1e-6f));
  }
  __syncthreads();
  if (tid == 0) {
    float loss = 0.f;
#pragma unroll
    for (int k = 0; k < 8; ++k) loss += sl[k];
    out[0] = loss * (1.0f / N_);
  }
}

extern "C" void kernel_launch(void* const* d_in, const int* in_sizes, int n_in,
                              void* d_out, int out_size, void* d_ws, size_t ws_size,
                              hipStream_t stream) {
  const float* rgb = (const float*)d_in[0];
  const float* ir = (const float*)d_in[1];
  float* out = (float*)d_out;

  unsigned short* rgbnT = (unsigned short*)d_ws;              // 4 MB
  unsigned short* irnT = rgbnT + (size_t)N_ * P_ * C_;        // 4 MB
  float* partials = (float*)(irnT + (size_t)N_ * P_ * C_);    // 8 KB

  dim3 g1(N_ * P_ / 256, 2);
  norm_transpose<<<g1, 256, 0, stream>>>(rgb, ir, rgbnT, irnT);

  gemm_exp_reduce<<<1024, 256, 0, stream>>>(rgbnT, irnT, partials);

  finalize<<<1, 1024, 0, stream>>>(partials, out);
}